// Round 4
// baseline (135.371 us; speedup 1.0000x reference)
//
#include <hip/hip_runtime.h>
#include <math.h>

#define NB 2
#define NQ 16384        // 32*512 downsampled points per batch
#define IN_H 64
#define IN_W 2048
#define BIG 1e30f
#define NQT (NB * NQ)
#define NG 8            // target groups (eighths)
#define NP (NG * 3)     // partial planes

typedef __bf16 bf16x8 __attribute__((ext_vector_type(8)));
typedef float f32x16 __attribute__((ext_vector_type(16)));

__device__ inline float med3(float a, float b, float c) {
    return __builtin_amdgcn_fmed3f(a, b, c);
}
// branchless sorted-insert of v into b0<=b1<=b2 (3 VALU)
#define INSERT3(B0, B1, B2, V)                    \
    do { float _v = (V);                          \
         (B2) = med3((B1), (B2), _v);             \
         (B1) = med3((B0), (B1), _v);             \
         (B0) = fminf((B0), _v); } while (0)

union PK { __bf16 h[8]; uint4 u; };

// ---------------------------------------------------------------------------
// pack_kernel: (a) bf16 compensated A-fragments for mfma_f32_32x32x16_bf16
// (layout verified, absmax 0.0), (b) compact fp32 float4 (x,y,z,||t||^2)
// per target for the exact pass-2 recompute (invalid -> xyz=0, w=1e20 so
// sqrt=1e10, matching the reference's INVALID_DIST). Also zeroes accum/done.
// ---------------------------------------------------------------------------
__global__ __launch_bounds__(256) void pack_kernel(
    const float* __restrict__ tgt_pc,   // [B,3,64,2048]
    uint4* __restrict__ packed,
    float4* __restrict__ tgt4,
    float* __restrict__ zws)
{
    if (blockIdx.x == 0 && threadIdx.x < 16) zws[threadIdx.x] = 0.f;

    int gid = blockIdx.x * 256 + threadIdx.x;   // [0, NB*NQ)
    int b = gid >> 14, t = gid & (NQ - 1);
    int oh = t >> 9, ow = t & 511;
    const size_t PL = (size_t)IN_H * IN_W;
    size_t base = ((size_t)(b * 3) * IN_H + oh * 2) * IN_W + ow * 4;
    float x = tgt_pc[base], y = tgt_pc[base + PL], z = tgt_pc[base + 2 * PL];
    bool valid = (x != 0.f) || (y != 0.f) || (z != 0.f);
    float ntx = x * x + y * y + z * z;
    float nt = valid ? ntx : BIG;               // pass-1 sentinel
    float tx = valid ? -2.f * x : 0.f;
    float ty = valid ? -2.f * y : 0.f;
    float tz = valid ? -2.f * z : 0.f;

    __bf16 txh = (__bf16)tx, tyh = (__bf16)ty, tzh = (__bf16)tz;
    __bf16 txl = (__bf16)(tx - (float)txh);
    __bf16 tyl = (__bf16)(ty - (float)tyh);
    __bf16 tzl = (__bf16)(tz - (float)tzh);
    __bf16 nth = (__bf16)nt;
    __bf16 ntl = (__bf16)(nt - (float)nth);

    PK h0, h1;
    h0.h[0] = txh; h0.h[1] = tyh; h0.h[2] = tzh; h0.h[3] = txh;
    h0.h[4] = tyh; h0.h[5] = tzh; h0.h[6] = txl; h0.h[7] = tyl;
    h1.h[0] = tzl; h1.h[1] = nth; h1.h[2] = ntl; h1.h[3] = (__bf16)1.0f;
    h1.h[4] = (__bf16)1.0f; h1.h[5] = (__bf16)0.0f;
    h1.h[6] = (__bf16)0.0f; h1.h[7] = (__bf16)0.0f;

    int tile = t >> 5, m = t & 31;
    size_t o = (size_t)(b * 512 + tile) * 64 + m;   // uint4 units
    packed[o]      = h0.u;   // k0..7
    packed[o + 32] = h1.u;   // k8..15

    // exact-recompute buffer: raw xyz (zeroed if invalid), w = nt or 1e20
    tgt4[gid] = make_float4(valid ? x : 0.f, valid ? y : 0.f,
                            valid ? z : 0.f, valid ? ntx : 1e20f);
}

// ---------------------------------------------------------------------------
// knn_mfma (R3/R4): NO LDS, NO barriers. packed (1 MB) is L2-resident; every
// wave streams its 64 tile-fragments directly from global (coalesced 1 KB
// uint4/wave), software-pipelined 4 tiles deep in registers. R2 post-mortem:
// occupancy 28->44% bought zero speedup; time tracked VALU-busy/0.42 in all
// configs -> the chunk barrier cadence (vmcnt(0)+syncthreads drain, 8x per
// block, all 4 waves in lockstep) was the bottleneck, not latency hiding.
// Waves now run fully independent. Two alternating INSERT3 chains halve the
// loop-carried dependency; merged exactly at the end.
// Pass 2 (exact fp32): recompute 3x16 candidate values from tgt4 per chain
// result, exact top-3, merge lane halves via shfl.
// ---------------------------------------------------------------------------
__global__ __launch_bounds__(256, 6) void knn_mfma(
    const float* __restrict__ src_pc,   // [B,64,2048,3]
    const uint4* __restrict__ packed,
    const float4* __restrict__ tgt4,
    float* __restrict__ partial)        // [NG][3][NQT] plane-major
{
    const int tid = threadIdx.x;
    const int lane = tid & 63;
    const int w = tid >> 6;
    int blk = blockIdx.x;
    int qt = blk & 127;
    int e8 = (blk >> 7) & 7;
    int b = blk >> 10;

    // ---- query-side B fragment (k = (lane>>5)*8 + j, col n = lane&31) ----
    int n = lane & 31;
    int q = qt * 128 + w * 32 + n;
    size_t sbase = (((size_t)b * IN_H + (q >> 9) * 2) * IN_W + (q & 511) * 4) * 3;
    float sx = src_pc[sbase], sy = src_pc[sbase + 1], sz = src_pc[sbase + 2];
    float ns = sx * sx + sy * sy + sz * sz;
    __bf16 sxh = (__bf16)sx, syh = (__bf16)sy, szh = (__bf16)sz;
    __bf16 sxl = (__bf16)(sx - (float)sxh);
    __bf16 syl = (__bf16)(sy - (float)syh);
    __bf16 szl = (__bf16)(sz - (float)szh);
    __bf16 nsh = (__bf16)ns;
    __bf16 nsl = (__bf16)(ns - (float)nsh);
    bf16x8 bq;
    if ((lane >> 5) == 0) {
        bq[0] = sxh; bq[1] = syh; bq[2] = szh; bq[3] = sxl;
        bq[4] = syl; bq[5] = szl; bq[6] = sxh; bq[7] = syh;
    } else {
        bq[0] = szh; bq[1] = (__bf16)1.0f; bq[2] = (__bf16)1.0f; bq[3] = nsh;
        bq[4] = nsl; bq[5] = (__bf16)0.0f; bq[6] = (__bf16)0.0f; bq[7] = (__bf16)0.0f;
    }

    f32x16 zero;
    #pragma unroll
    for (int i = 0; i < 16; ++i) zero[i] = 0.f;

    // two independent packed (min | tile-idx) top-3 chains (even/odd tiles)
    float c0a = BIG, c1a = BIG, c2a = BIG;
    float c0b = BIG, c1b = BIG, c2b = BIG;

    const uint4* pkq = packed + (size_t)b * 32768 + (size_t)e8 * 4096 + lane;

    uint4 cur[4];
    #pragma unroll
    for (int i = 0; i < 4; ++i) cur[i] = pkq[i * 64];

    for (int tt = 0; tt < 64; tt += 4) {
        uint4 nxt[4];
        if (tt + 4 < 64) {
            #pragma unroll
            for (int i = 0; i < 4; ++i) nxt[i] = pkq[(tt + 4 + i) * 64];
        }
        #pragma unroll
        for (int i = 0; i < 4; ++i) {
            bf16x8 af = __builtin_bit_cast(bf16x8, cur[i]);
            f32x16 d = __builtin_amdgcn_mfma_f32_32x32x16_bf16(af, bq, zero, 0, 0, 0);
            // min of 16 (fminf nest -> fused v_min3 tree, ~8 ops)
            float m0 = fminf(fminf(d[0], d[1]), fminf(d[2], d[3]));
            float m1 = fminf(fminf(d[4], d[5]), fminf(d[6], d[7]));
            float m2 = fminf(fminf(d[8], d[9]), fminf(d[10], d[11]));
            float m3 = fminf(fminf(d[12], d[13]), fminf(d[14], d[15]));
            float m = fminf(fminf(m0, m1), fminf(m2, m3));
            // pack tile index (0..63) into low 6 mantissa bits
            unsigned u = (__float_as_uint(m) & ~63u) | (unsigned)(tt + i);
            float pv = __uint_as_float(u);
            if (i & 1) { INSERT3(c0b, c1b, c2b, pv); }
            else       { INSERT3(c0a, c1a, c2a, pv); }
        }
        if (tt + 4 < 64) {
            #pragma unroll
            for (int i = 0; i < 4; ++i) cur[i] = nxt[i];
        }
    }
    // exact merge of the two chains: top3(A u B) from top3(A), top3(B)
    INSERT3(c0a, c1a, c2a, c0b);
    INSERT3(c0a, c1a, c2a, c1b);
    INSERT3(c0a, c1a, c2a, c2b);

    // ---- pass 2: exact fp32 recompute of the 3 candidate tiles ----
    int half = lane >> 5;
    int ti[3] = { (int)(__float_as_uint(c0a) & 63u),
                  (int)(__float_as_uint(c1a) & 63u),
                  (int)(__float_as_uint(c2a) & 63u) };
    float e0 = BIG, e1 = BIG, e2 = BIG;
    const float4* t4b = tgt4 + (size_t)b * NQ + (size_t)e8 * 2048;
    #pragma unroll
    for (int i = 0; i < 3; ++i) {
        int tbase = ti[i] * 32 + 4 * half;
        #pragma unroll
        for (int rr = 0; rr < 16; ++rr) {
            int row = (rr & 3) + 8 * (rr >> 2);     // + 4*half folded in tbase
            float4 t4 = t4b[tbase + row];
            float dot = sx * t4.x;
            dot = fmaf(sy, t4.y, dot);
            dot = fmaf(sz, t4.z, dot);
            float d2 = fmaf(-2.f, dot, ns + t4.w);  // exact-form d^2
            INSERT3(e0, e1, e2, d2);
        }
    }

    // ---- merge lane halves (L <- L+32, same query col), write planes ----
    float f0 = __shfl_down(e0, 32, 64);
    float f1 = __shfl_down(e1, 32, 64);
    float f2 = __shfl_down(e2, 32, 64);
    if (lane < 32) {
        INSERT3(e0, e1, e2, f0);
        INSERT3(e0, e1, e2, f1);
        INSERT3(e0, e1, e2, f2);
        int gq = b * NQ + q;
        partial[(e8 * 3 + 0) * NQT + gq] = e0;
        partial[(e8 * 3 + 1) * NQT + gq] = e1;
        partial[(e8 * 3 + 2) * NQT + gq] = e2;
    }
}

// ---------------------------------------------------------------------------
// merge_final: per query merge 8 eighth-trios, sqrt+clamp, masked reduce,
// per-batch atomics; last finished block computes the scalar output.
// ---------------------------------------------------------------------------
__global__ __launch_bounds__(256) void merge_final(
    const float* __restrict__ partial,
    const float* __restrict__ src_pc,
    float* __restrict__ accum,          // {sum0,cnt0,sum1,cnt1}
    int* __restrict__ done_cnt,
    float* __restrict__ out)
{
    int gid = blockIdx.x * 256 + threadIdx.x;   // < NQT
    int b = gid >> 14;
    int q = gid & (NQ - 1);

    float b0 = BIG, b1 = BIG, b2 = BIG;
    #pragma unroll
    for (int c = 0; c < NP; ++c) {
        float v = partial[c * NQT + gid];       // coalesced plane reads
        INSERT3(b0, b1, b2, v);
    }

    size_t base = (((size_t)b * IN_H + (q >> 9) * 2) * IN_W + (q & 511) * 4) * 3;
    float x = src_pc[base], y = src_pc[base + 1], z = src_pc[base + 2];
    float wt = ((x != 0.f) || (y != 0.f) || (z != 0.f)) ? 1.f : 0.f;

    float d = fminf(sqrtf(fmaxf(b0, 0.f)), 1e10f)
            + fminf(sqrtf(fmaxf(b1, 0.f)), 1e10f)
            + fminf(sqrtf(fmaxf(b2, 0.f)), 1e10f);
    float dsum = d * wt;

    #pragma unroll
    for (int off = 32; off > 0; off >>= 1) {
        dsum += __shfl_down(dsum, off, 64);
        wt   += __shfl_down(wt, off, 64);
    }
    __shared__ float sd[4], sw4[4];
    int lane = threadIdx.x & 63, wv = threadIdx.x >> 6;
    if (lane == 0) { sd[wv] = dsum; sw4[wv] = wt; }
    __syncthreads();
    if (threadIdx.x == 0) {
        atomicAdd(&accum[b * 2 + 0], sd[0] + sd[1] + sd[2] + sd[3]);
        atomicAdd(&accum[b * 2 + 1], sw4[0] + sw4[1] + sw4[2] + sw4[3]);
        __threadfence();
        int done = atomicAdd(done_cnt, 1);
        if (done == (int)gridDim.x - 1) {
            float s0 = atomicAdd(&accum[0], 0.f);
            float c0 = atomicAdd(&accum[1], 0.f);
            float s1 = atomicAdd(&accum[2], 0.f);
            float c1 = atomicAdd(&accum[3], 0.f);
            float r = s0 / (3.0f * fmaxf(c0, 1.0f))
                    + s1 / (3.0f * fmaxf(c1, 1.0f));
            out[0] = r / (float)NB;
        }
    }
}

// ---------------------------------------------------------------------------
extern "C" void kernel_launch(void* const* d_in, const int* in_sizes, int n_in,
                              void* d_out, int out_size, void* d_ws, size_t ws_size,
                              hipStream_t stream) {
    const float* src_pc = (const float*)d_in[0];   // [2,64,2048,3]
    const float* tgt_pc = (const float*)d_in[1];   // [2,3,64,2048]
    float* out = (float*)d_out;

    char* ws = (char*)d_ws;
    float*  accum   = (float*)ws;                   // 4 floats @ 0
    int*    done    = (int*)(ws + 32);              // 1 int    @ 32
    float*  partial = (float*)(ws + 64);            // 24 planes = 3 MB
    uint4*  packed  = (uint4*)(ws + 3145792);       // 1 MB
    float4* tgt4    = (float4*)(ws + 4194368);      // 512 KB

    pack_kernel<<<NQT / 256, 256, 0, stream>>>(tgt_pc, packed, tgt4, (float*)ws);
    knn_mfma<<<NB * NG * 128, 256, 0, stream>>>(src_pc, packed, tgt4, partial);
    merge_final<<<NQT / 256, 256, 0, stream>>>(partial, src_pc, accum, done, out);
}

// Round 5
// 108.375 us; speedup vs baseline: 1.2491x; 1.2491x over previous
//
#include <hip/hip_runtime.h>
#include <math.h>

#define NB 2
#define NQ 16384        // 32*512 downsampled points per batch
#define IN_H 64
#define IN_W 2048
#define BIG 1e30f
#define NQT (NB * NQ)
#define NG 4            // target groups (quarters) — R4 post-mortem: NG=8 only added pass-2 work
#define NP (NG * 3)     // partial planes

typedef __bf16 bf16x8 __attribute__((ext_vector_type(8)));
typedef float f32x16 __attribute__((ext_vector_type(16)));

__device__ inline float med3(float a, float b, float c) {
    return __builtin_amdgcn_fmed3f(a, b, c);
}
// branchless sorted-insert of v into b0<=b1<=b2 (3 VALU)
#define INSERT3(B0, B1, B2, V)                    \
    do { float _v = (V);                          \
         (B2) = med3((B1), (B2), _v);             \
         (B1) = med3((B0), (B1), _v);             \
         (B0) = fminf((B0), _v); } while (0)

union PK { __bf16 h[8]; uint4 u; };

// ---------------------------------------------------------------------------
// pack_kernel: (a) bf16 compensated A-fragments for mfma_f32_32x32x16_bf16
// (layout verified, absmax 0.0), (b) compact fp32 float4 (x,y,z,||t||^2)
// per target for the exact pass-2 recompute (invalid -> xyz=0, w=1e20 so
// sqrt=1e10, matching the reference's INVALID_DIST). Also zeroes accum/done.
// ---------------------------------------------------------------------------
__global__ __launch_bounds__(256) void pack_kernel(
    const float* __restrict__ tgt_pc,   // [B,3,64,2048]
    uint4* __restrict__ packed,
    float4* __restrict__ tgt4,
    float* __restrict__ zws)
{
    if (blockIdx.x == 0 && threadIdx.x < 16) zws[threadIdx.x] = 0.f;

    int gid = blockIdx.x * 256 + threadIdx.x;   // [0, NB*NQ)
    int b = gid >> 14, t = gid & (NQ - 1);
    int oh = t >> 9, ow = t & 511;
    const size_t PL = (size_t)IN_H * IN_W;
    size_t base = ((size_t)(b * 3) * IN_H + oh * 2) * IN_W + ow * 4;
    float x = tgt_pc[base], y = tgt_pc[base + PL], z = tgt_pc[base + 2 * PL];
    bool valid = (x != 0.f) || (y != 0.f) || (z != 0.f);
    float ntx = x * x + y * y + z * z;
    float nt = valid ? ntx : BIG;               // pass-1 sentinel
    float tx = valid ? -2.f * x : 0.f;
    float ty = valid ? -2.f * y : 0.f;
    float tz = valid ? -2.f * z : 0.f;

    __bf16 txh = (__bf16)tx, tyh = (__bf16)ty, tzh = (__bf16)tz;
    __bf16 txl = (__bf16)(tx - (float)txh);
    __bf16 tyl = (__bf16)(ty - (float)tyh);
    __bf16 tzl = (__bf16)(tz - (float)tzh);
    __bf16 nth = (__bf16)nt;
    __bf16 ntl = (__bf16)(nt - (float)nth);

    PK h0, h1;
    h0.h[0] = txh; h0.h[1] = tyh; h0.h[2] = tzh; h0.h[3] = txh;
    h0.h[4] = tyh; h0.h[5] = tzh; h0.h[6] = txl; h0.h[7] = tyl;
    h1.h[0] = tzl; h1.h[1] = nth; h1.h[2] = ntl; h1.h[3] = (__bf16)1.0f;
    h1.h[4] = (__bf16)1.0f; h1.h[5] = (__bf16)0.0f;
    h1.h[6] = (__bf16)0.0f; h1.h[7] = (__bf16)0.0f;

    int tile = t >> 5, m = t & 31;
    size_t o = (size_t)(b * 512 + tile) * 64 + m;   // uint4 units
    packed[o]      = h0.u;   // k0..7
    packed[o + 32] = h1.u;   // k8..15

    // exact-recompute buffer: raw xyz (zeroed if invalid), w = nt or 1e20
    tgt4[gid] = make_float4(valid ? x : 0.f, valid ? y : 0.f,
                            valid ? z : 0.f, valid ? ntx : 1e20f);
}

// ---------------------------------------------------------------------------
// knn_mfma (R5): no LDS, no barriers (kept from R4), but the pass-1 loop is
// now FULLY UNROLLED with named ping-pong buffers bufA/bufB:
//  - zero register-rotation copies (R4 did ~4 mov/tile for cur<-nxt),
//  - every load offset and tile index is a compile-time constant (R4's
//    runtime (tt+4+i)*64 indexing cost ~3 VALU/tile and pushed staging into
//    AGPR round-trips: VGPR_Count=36 + VALU 3x my hand count),
//  - 8-deep prefetch: ~272 cyc compute per 8-tile group covers L2 latency
//    (~200-400 cyc) where R4's 4-deep (~136 cyc) stalled every group.
// launch_bounds(256,4): 128-VGPR budget for the ~100 the ping-pong needs;
// grid = NB*4*128 = 1024 = 4 blocks/CU (grid-limited anyway).
// Pass 2 (exact fp32): recompute 3x16 candidate values from tgt4, exact
// top-3, merge lane halves via shfl.  NG=4: half of R4's pass-2/merge work.
// ---------------------------------------------------------------------------
#define COMPUTE_TILE(U, IDX)                                                  \
    do {                                                                      \
        bf16x8 af = __builtin_bit_cast(bf16x8, (U));                          \
        f32x16 d = __builtin_amdgcn_mfma_f32_32x32x16_bf16(af, bq, zero, 0, 0, 0); \
        float m0 = fminf(fminf(d[0], d[1]), fminf(d[2], d[3]));               \
        float m1 = fminf(fminf(d[4], d[5]), fminf(d[6], d[7]));               \
        float m2 = fminf(fminf(d[8], d[9]), fminf(d[10], d[11]));             \
        float m3 = fminf(fminf(d[12], d[13]), fminf(d[14], d[15]));           \
        float m = fminf(fminf(m0, m1), fminf(m2, m3));                        \
        unsigned u = (__float_as_uint(m) & ~127u) | (unsigned)(IDX);          \
        float pv = __uint_as_float(u);                                        \
        if ((IDX) & 1) { INSERT3(c0b, c1b, c2b, pv); }                        \
        else           { INSERT3(c0a, c1a, c2a, pv); }                        \
    } while (0)

__global__ __launch_bounds__(256, 4) void knn_mfma(
    const float* __restrict__ src_pc,   // [B,64,2048,3]
    const uint4* __restrict__ packed,
    const float4* __restrict__ tgt4,
    float* __restrict__ partial)        // [NG][3][NQT] plane-major
{
    const int tid = threadIdx.x;
    const int lane = tid & 63;
    const int w = tid >> 6;
    int blk = blockIdx.x;
    int qt = blk & 127;
    int quarter = (blk >> 7) & 3;
    int b = blk >> 9;

    // ---- query-side B fragment (k = (lane>>5)*8 + j, col n = lane&31) ----
    int n = lane & 31;
    int q = qt * 128 + w * 32 + n;
    size_t sbase = (((size_t)b * IN_H + (q >> 9) * 2) * IN_W + (q & 511) * 4) * 3;
    float sx = src_pc[sbase], sy = src_pc[sbase + 1], sz = src_pc[sbase + 2];
    float ns = sx * sx + sy * sy + sz * sz;
    __bf16 sxh = (__bf16)sx, syh = (__bf16)sy, szh = (__bf16)sz;
    __bf16 sxl = (__bf16)(sx - (float)sxh);
    __bf16 syl = (__bf16)(sy - (float)syh);
    __bf16 szl = (__bf16)(sz - (float)szh);
    __bf16 nsh = (__bf16)ns;
    __bf16 nsl = (__bf16)(ns - (float)nsh);
    bf16x8 bq;
    if ((lane >> 5) == 0) {
        bq[0] = sxh; bq[1] = syh; bq[2] = szh; bq[3] = sxl;
        bq[4] = syl; bq[5] = szl; bq[6] = sxh; bq[7] = syh;
    } else {
        bq[0] = szh; bq[1] = (__bf16)1.0f; bq[2] = (__bf16)1.0f; bq[3] = nsh;
        bq[4] = nsl; bq[5] = (__bf16)0.0f; bq[6] = (__bf16)0.0f; bq[7] = (__bf16)0.0f;
    }

    f32x16 zero;
    #pragma unroll
    for (int i = 0; i < 16; ++i) zero[i] = 0.f;

    // two independent packed (min | tile-idx) top-3 chains (even/odd tiles)
    float c0a = BIG, c1a = BIG, c2a = BIG;
    float c0b = BIG, c1b = BIG, c2b = BIG;

    const uint4* pkq = packed + (size_t)b * 32768 + (size_t)quarter * 8192 + lane;

    // ---- pass 1: 128 tiles, fully unrolled, 8-tile ping-pong pipeline ----
    uint4 bufA[8], bufB[8];
    #pragma unroll
    for (int i = 0; i < 8; ++i) bufA[i] = pkq[i * 64];      // group 0

    #pragma unroll
    for (int gg = 0; gg < 8; ++gg) {
        // prefetch odd group 2*gg+1 into bufB, compute even group 2*gg (bufA)
        #pragma unroll
        for (int i = 0; i < 8; ++i) bufB[i] = pkq[((2 * gg + 1) * 8 + i) * 64];
        #pragma unroll
        for (int i = 0; i < 8; ++i) COMPUTE_TILE(bufA[i], 2 * gg * 8 + i);
        // prefetch even group 2*gg+2 into bufA, compute odd group 2*gg+1 (bufB)
        if (gg < 7) {
            #pragma unroll
            for (int i = 0; i < 8; ++i) bufA[i] = pkq[((2 * gg + 2) * 8 + i) * 64];
        }
        #pragma unroll
        for (int i = 0; i < 8; ++i) COMPUTE_TILE(bufB[i], (2 * gg + 1) * 8 + i);
    }

    // exact merge of the two chains: top3(A u B) from top3(A), top3(B)
    INSERT3(c0a, c1a, c2a, c0b);
    INSERT3(c0a, c1a, c2a, c1b);
    INSERT3(c0a, c1a, c2a, c2b);

    // ---- pass 2: exact fp32 recompute of the 3 candidate tiles ----
    int half = lane >> 5;
    int ti[3] = { (int)(__float_as_uint(c0a) & 127u),
                  (int)(__float_as_uint(c1a) & 127u),
                  (int)(__float_as_uint(c2a) & 127u) };
    float e0 = BIG, e1 = BIG, e2 = BIG;
    const float4* t4b = tgt4 + (size_t)b * NQ + (size_t)quarter * 4096;
    #pragma unroll
    for (int i = 0; i < 3; ++i) {
        int tbase = ti[i] * 32 + 4 * half;
        #pragma unroll
        for (int rr = 0; rr < 16; ++rr) {
            int row = (rr & 3) + 8 * (rr >> 2);     // + 4*half folded in tbase
            float4 t4 = t4b[tbase + row];
            float dot = sx * t4.x;
            dot = fmaf(sy, t4.y, dot);
            dot = fmaf(sz, t4.z, dot);
            float d2 = fmaf(-2.f, dot, ns + t4.w);  // exact-form d^2
            INSERT3(e0, e1, e2, d2);
        }
    }

    // ---- merge lane halves (L <- L+32, same query col), write planes ----
    float f0 = __shfl_down(e0, 32, 64);
    float f1 = __shfl_down(e1, 32, 64);
    float f2 = __shfl_down(e2, 32, 64);
    if (lane < 32) {
        INSERT3(e0, e1, e2, f0);
        INSERT3(e0, e1, e2, f1);
        INSERT3(e0, e1, e2, f2);
        int gq = b * NQ + q;
        partial[(quarter * 3 + 0) * NQT + gq] = e0;
        partial[(quarter * 3 + 1) * NQT + gq] = e1;
        partial[(quarter * 3 + 2) * NQT + gq] = e2;
    }
}

// ---------------------------------------------------------------------------
// merge_final: per query merge 4 quarter-trios, sqrt+clamp, masked reduce,
// per-batch atomics; last finished block computes the scalar output.
// ---------------------------------------------------------------------------
__global__ __launch_bounds__(256) void merge_final(
    const float* __restrict__ partial,
    const float* __restrict__ src_pc,
    float* __restrict__ accum,          // {sum0,cnt0,sum1,cnt1}
    int* __restrict__ done_cnt,
    float* __restrict__ out)
{
    int gid = blockIdx.x * 256 + threadIdx.x;   // < NQT
    int b = gid >> 14;
    int q = gid & (NQ - 1);

    float b0 = BIG, b1 = BIG, b2 = BIG;
    #pragma unroll
    for (int c = 0; c < NP; ++c) {
        float v = partial[c * NQT + gid];       // coalesced plane reads
        INSERT3(b0, b1, b2, v);
    }

    size_t base = (((size_t)b * IN_H + (q >> 9) * 2) * IN_W + (q & 511) * 4) * 3;
    float x = src_pc[base], y = src_pc[base + 1], z = src_pc[base + 2];
    float wt = ((x != 0.f) || (y != 0.f) || (z != 0.f)) ? 1.f : 0.f;

    float d = fminf(sqrtf(fmaxf(b0, 0.f)), 1e10f)
            + fminf(sqrtf(fmaxf(b1, 0.f)), 1e10f)
            + fminf(sqrtf(fmaxf(b2, 0.f)), 1e10f);
    float dsum = d * wt;

    #pragma unroll
    for (int off = 32; off > 0; off >>= 1) {
        dsum += __shfl_down(dsum, off, 64);
        wt   += __shfl_down(wt, off, 64);
    }
    __shared__ float sd[4], sw4[4];
    int lane = threadIdx.x & 63, wv = threadIdx.x >> 6;
    if (lane == 0) { sd[wv] = dsum; sw4[wv] = wt; }
    __syncthreads();
    if (threadIdx.x == 0) {
        atomicAdd(&accum[b * 2 + 0], sd[0] + sd[1] + sd[2] + sd[3]);
        atomicAdd(&accum[b * 2 + 1], sw4[0] + sw4[1] + sw4[2] + sw4[3]);
        __threadfence();
        int done = atomicAdd(done_cnt, 1);
        if (done == (int)gridDim.x - 1) {
            float s0 = atomicAdd(&accum[0], 0.f);
            float c0 = atomicAdd(&accum[1], 0.f);
            float s1 = atomicAdd(&accum[2], 0.f);
            float c1 = atomicAdd(&accum[3], 0.f);
            float r = s0 / (3.0f * fmaxf(c0, 1.0f))
                    + s1 / (3.0f * fmaxf(c1, 1.0f));
            out[0] = r / (float)NB;
        }
    }
}

// ---------------------------------------------------------------------------
extern "C" void kernel_launch(void* const* d_in, const int* in_sizes, int n_in,
                              void* d_out, int out_size, void* d_ws, size_t ws_size,
                              hipStream_t stream) {
    const float* src_pc = (const float*)d_in[0];   // [2,64,2048,3]
    const float* tgt_pc = (const float*)d_in[1];   // [2,3,64,2048]
    float* out = (float*)d_out;

    char* ws = (char*)d_ws;
    float*  accum   = (float*)ws;                   // 4 floats @ 0
    int*    done    = (int*)(ws + 32);              // 1 int    @ 32
    float*  partial = (float*)(ws + 64);            // 12 planes = 1.5 MB
    uint4*  packed  = (uint4*)(ws + 2097152);       // 1 MB
    float4* tgt4    = (float4*)(ws + 3145728);      // 512 KB

    pack_kernel<<<NQT / 256, 256, 0, stream>>>(tgt_pc, packed, tgt4, (float*)ws);
    knn_mfma<<<NB * NG * 128, 256, 0, stream>>>(src_pc, packed, tgt4, partial);
    merge_final<<<NQT / 256, 256, 0, stream>>>(partial, src_pc, accum, done, out);
}